// Round 1
// baseline (1124.879 us; speedup 1.0000x reference)
//
#include <hip/hip_runtime.h>
#include <hip/hip_fp16.h>
#include <stdint.h>

typedef _Float16 f16;
typedef _Float16 f16x8 __attribute__((ext_vector_type(8)));
typedef float f32x4 __attribute__((ext_vector_type(4)));

// async global->LDS, 16B per lane; LDS dest is wave-uniform base + lane*16
__device__ __forceinline__ void gload_lds16(const void* g, void* l) {
    __builtin_amdgcn_global_load_lds(
        (const __attribute__((address_space(1))) void*)g,
        (__attribute__((address_space(3))) void*)l,
        16, 0, 0);
}

// ---------------- kernel 0a: X fp32 -> f16 ----------------
__global__ __launch_bounds__(256) void convert_x(const float* __restrict__ X,
                                                 f16* __restrict__ Xh) {
    size_t i = ((size_t)blockIdx.x * 256 + threadIdx.x) * 8;
    float4 a = *(const float4*)(X + i);
    float4 b = *(const float4*)(X + i + 4);
    f16x8 o;
    o[0] = (f16)a.x; o[1] = (f16)a.y; o[2] = (f16)a.z; o[3] = (f16)a.w;
    o[4] = (f16)b.x; o[5] = (f16)b.y; o[6] = (f16)b.z; o[7] = (f16)b.w;
    *(f16x8*)(Xh + i) = o;
}

// ---------------- kernel 0b: W [K][N] fp32 -> Wt [3N][K] f16 ----------------
__global__ __launch_bounds__(1024) void transpose_w(const float* __restrict__ Wq,
                                                    const float* __restrict__ Wk,
                                                    const float* __restrict__ Wv,
                                                    f16* __restrict__ Wt) {
    __shared__ float tile[32][33];
    const int w = blockIdx.z;
    const float* W = (w == 0) ? Wq : ((w == 1) ? Wk : Wv);
    const int n0 = blockIdx.x * 32, k0 = blockIdx.y * 32;
    const int tx = threadIdx.x, ty = threadIdx.y;
    tile[ty][tx] = W[(size_t)(k0 + ty) * 1024 + n0 + tx];
    __syncthreads();
    Wt[(size_t)(w * 1024 + n0 + ty) * 1024 + k0 + tx] = (f16)tile[tx][ty];
}

// ---------------- kernel 1: QKV = X @ W + b  (m97-style 128x128 tile) -------
// A: Xh [65536][1024] f16, Bt: Wt [3072][1024] f16 (row n, contiguous k)
// Out: 3 buffers [B=1024][H=16][L=64][D=64] f16
__global__ __launch_bounds__(256) void qkv_gemm(const f16* __restrict__ A,
                                                const f16* __restrict__ Bt,
                                                const float* __restrict__ bq,
                                                const float* __restrict__ bk,
                                                const float* __restrict__ bv,
                                                f16* __restrict__ Out) {
    __shared__ __align__(16) f16 sA[128][32];
    __shared__ __align__(16) f16 sB[128][32];

    const int tid  = threadIdx.x;
    const int wave = tid >> 6, lane = tid & 63;
    const int quad = lane >> 4, l16 = lane & 15;
    const int m0 = blockIdx.y * 128, n0 = blockIdx.x * 128;
    const int wm = (wave & 1) * 64, wn = (wave >> 1) * 64;

    // staging: wave covers 32 rows (2 ops x 16 rows); lane i -> row i/4, col (i%4)*8
    const int srow = lane >> 2;
    const int scol = (lane & 3) * 8;
    const f16* gA = A  + (size_t)(m0 + wave * 32 + srow) * 1024 + scol;
    const f16* gB = Bt + (size_t)(n0 + wave * 32 + srow) * 1024 + scol;
    f16* lA = &sA[wave * 32][0];
    f16* lB = &sB[wave * 32][0];

    f32x4 acc[4][4] = {};

    for (int k0 = 0; k0 < 1024; k0 += 32) {
        gload_lds16(gA + k0,             lA);
        gload_lds16(gA + k0 + 16 * 1024, lA + 16 * 32);
        gload_lds16(gB + k0,             lB);
        gload_lds16(gB + k0 + 16 * 1024, lB + 16 * 32);
        __syncthreads();   // drains vmcnt before barrier

        f16x8 af[4], bf[4];
#pragma unroll
        for (int t = 0; t < 4; ++t)
            af[t] = *(const f16x8*)&sA[wm + t * 16 + l16][quad * 8];
#pragma unroll
        for (int t = 0; t < 4; ++t)
            bf[t] = *(const f16x8*)&sB[wn + t * 16 + l16][quad * 8];

#pragma unroll
        for (int mt = 0; mt < 4; ++mt)
#pragma unroll
            for (int nt = 0; nt < 4; ++nt)
                acc[mt][nt] = __builtin_amdgcn_mfma_f32_16x16x32_f16(
                    af[mt], bf[nt], acc[mt][nt], 0, 0, 0);
        __syncthreads();
    }

    // epilogue: +bias, f16 store into [B][H][L][D]
    const int w_idx = n0 >> 10;                 // 128 | 1024 -> block-uniform
    const float* bias = (w_idx == 0) ? bq : ((w_idx == 1) ? bk : bv);
    f16* out = Out + (size_t)w_idx * (65536UL * 1024UL);
#pragma unroll
    for (int mt = 0; mt < 4; ++mt) {
#pragma unroll
        for (int r = 0; r < 4; ++r) {
            const int m = m0 + wm + mt * 16 + quad * 4 + r;
            const int b = m >> 6, l = m & 63;
#pragma unroll
            for (int nt = 0; nt < 4; ++nt) {
                const int n  = n0 + wn + nt * 16 + l16;
                const int nc = n & 1023;
                const int h = nc >> 6, d = nc & 63;
                const float v = acc[mt][nt][r] + bias[nc];
                out[(((size_t)b * 16 + h) * 64 + l) * 64 + d] = (f16)v;
            }
        }
    }
}

// ---------------- kernel 2: attention per (b,h) -----------------------------
__global__ __launch_bounds__(256) void attn(const f16* __restrict__ QKV,
                                            const float* __restrict__ bias_table,
                                            float* __restrict__ outp) {
    __shared__ __align__(16) f16 sQ[64][72];   // reused as sP after softmax
    __shared__ __align__(16) f16 sK[64][72];
    __shared__ __align__(16) f16 sVt[64][72];  // transposed: [d][l]
    __shared__ float sS[64][66];
    __shared__ float sR[64];

    const int bh = blockIdx.x;
    const int h  = bh & 15;
    const int tid  = threadIdx.x;
    const int wave = tid >> 6, lane = tid & 63;
    const int quad = lane >> 4, l16 = lane & 15;

    const f16* Qg = QKV + (size_t)bh * 4096;
    const f16* Kg = Qg + 65536UL * 1024UL;
    const f16* Vg = Kg + 65536UL * 1024UL;

    // stage Q,K (row-major) and V transposed
#pragma unroll
    for (int j = 0; j < 2; ++j) {
        const int idx = tid + j * 256;     // 0..511 chunks of 8 f16
        const int e = idx * 8;
        const int l = e >> 6, d = e & 63;
        *(f16x8*)&sQ[l][d] = *(const f16x8*)(Qg + e);
        *(f16x8*)&sK[l][d] = *(const f16x8*)(Kg + e);
        f16x8 v = *(const f16x8*)(Vg + e);
#pragma unroll
        for (int i = 0; i < 8; ++i) sVt[d + i][l] = v[i];
    }
    __syncthreads();

    // S = Q K^T / 8 + rel_bias ; wave handles rows [wave*16, wave*16+16)
    {
        f32x4 acc[4] = {};
#pragma unroll
        for (int k0 = 0; k0 < 64; k0 += 32) {
            f16x8 a = *(const f16x8*)&sQ[wave * 16 + l16][k0 + quad * 8];
#pragma unroll
            for (int nt = 0; nt < 4; ++nt) {
                f16x8 b = *(const f16x8*)&sK[nt * 16 + l16][k0 + quad * 8];
                acc[nt] = __builtin_amdgcn_mfma_f32_16x16x32_f16(a, b, acc[nt], 0, 0, 0);
            }
        }
#pragma unroll
        for (int nt = 0; nt < 4; ++nt) {
            const int jcol = nt * 16 + l16;
#pragma unroll
            for (int r = 0; r < 4; ++r) {
                const int i = wave * 16 + quad * 4 + r;
                // rel_index[i][j] = i - j + 63
                const float bias = bias_table[(i - jcol + 63) * 16 + h];
                sS[i][jcol] = acc[nt][r] * 0.125f + bias;
            }
        }
    }
    __syncthreads();

    // row softmax (fp32), P stored f16 unnormalized into sQ, 1/sum into sR
    if (tid < 64) {
        float mx = -1e30f;
#pragma unroll
        for (int j = 0; j < 64; ++j) mx = fmaxf(mx, sS[tid][j]);
        float sum = 0.f;
#pragma unroll
        for (int j = 0; j < 64; ++j) {
            const float e = __expf(sS[tid][j] - mx);
            sum += e;
            sQ[tid][j] = (f16)e;
        }
        sR[tid] = 1.0f / sum;
    }
    __syncthreads();

    // context = (P @ V) * (1/sum)  ; A = P [i][l], B = Vt [d][l]
    {
        f32x4 acc[4] = {};
#pragma unroll
        for (int k0 = 0; k0 < 64; k0 += 32) {
            f16x8 a = *(const f16x8*)&sQ[wave * 16 + l16][k0 + quad * 8];
#pragma unroll
            for (int nt = 0; nt < 4; ++nt) {
                f16x8 b = *(const f16x8*)&sVt[nt * 16 + l16][k0 + quad * 8];
                acc[nt] = __builtin_amdgcn_mfma_f32_16x16x32_f16(a, b, acc[nt], 0, 0, 0);
            }
        }
        const int b = bh >> 4;
#pragma unroll
        for (int nt = 0; nt < 4; ++nt) {
            const int d = nt * 16 + l16;
#pragma unroll
            for (int r = 0; r < 4; ++r) {
                const int i = wave * 16 + quad * 4 + r;
                outp[((size_t)b * 64 + i) * 1024 + h * 64 + d] = acc[nt][r] * sR[i];
            }
        }
    }
}

extern "C" void kernel_launch(void* const* d_in, const int* in_sizes, int n_in,
                              void* d_out, int out_size, void* d_ws, size_t ws_size,
                              hipStream_t stream) {
    const float* X          = (const float*)d_in[0];
    const float* Wq         = (const float*)d_in[1];
    const float* bq         = (const float*)d_in[2];
    const float* Wk         = (const float*)d_in[3];
    const float* bk         = (const float*)d_in[4];
    const float* Wv         = (const float*)d_in[5];
    const float* bv         = (const float*)d_in[6];
    const float* bias_table = (const float*)d_in[7];
    // d_in[8] rel_index: computed analytically (i - j + 63)
    float* out = (float*)d_out;

    // workspace layout (f16): Xh 67108864 | Wt 3145728 | QKV 3*67108864
    f16* Xh  = (f16*)d_ws;
    f16* Wt  = Xh + 67108864UL;
    f16* QKV = Wt + 3145728UL;

    convert_x<<<32768, 256, 0, stream>>>(X, Xh);
    transpose_w<<<dim3(32, 32, 3), dim3(32, 32), 0, stream>>>(Wq, Wk, Wv, Wt);
    qkv_gemm<<<dim3(24, 512), 256, 0, stream>>>(Xh, Wt, bq, bk, bv, QKV);
    attn<<<16384, 256, 0, stream>>>(QKV, bias_table, out);
}